// Round 2
// baseline (7313.313 us; speedup 1.0000x reference)
//
#include <hip/hip_runtime.h>
#include <hip/hip_bf16.h>
#include <math.h>

#define HEADS  8
#define DHEAD  64
#define ROT    32            // rotary dims = DHEAD/2
#define TT     32            // T (sequence length along time axis)
#define DMODEL 512
#define HWSZ   (32*32)       // H*W
#define TSTRIDE (HWSZ*DMODEL) // element stride between consecutive t for fixed (b,hw)

// One block per attention group n = (b,h,w).  256 threads.
// Fused: qkv GEMM -> RoPE -> causal softmax -> PV -> out-projection (+bias).
__global__ __launch_bounds__(256)
void taa_fused_kernel(const float* __restrict__ x,
                      const float* __restrict__ w_qkv,
                      const float* __restrict__ w_out,
                      const float* __restrict__ b_out,
                      float* __restrict__ out)
{
    __shared__ __align__(16) float x_tile[TT][DMODEL];   // 64 KB
    __shared__ float q_s[TT][DHEAD + 1];                 // +1 pad: banks
    __shared__ float k_s[TT][DHEAD + 1];
    __shared__ float v_s[TT][DHEAD + 1];
    __shared__ float s_s[TT][TT + 1];                    // scores / probs
    __shared__ float pv_s[TT][DHEAD + 1];                // per-head attn output
    __shared__ float cs_tab[TT][ROT / 2];                // cos table
    __shared__ float sn_tab[TT][ROT / 2];                // sin table

    const int tid = threadIdx.x;
    const int n   = blockIdx.x;          // 0..2047
    const int b   = n / HWSZ;
    const int hw  = n % HWSZ;
    const long long base = ((long long)b * TT * HWSZ + hw) * DMODEL;

    // ---- cos/sin tables (once per block) ----
    // BUGFIX r1: 512 entries but only 256 threads -> grid-stride loop
    // (previous `if (tid < 512)` left rows t=16..31 uninitialized).
    for (int i = tid; i < TT * (ROT / 2); i += 256) {
        int r = i >> 4;                  // t
        int j = i & 15;                  // frequency index
        float inv = powf(10000.f, -(float)(2 * j) / (float)ROT);
        float ang = (float)r * inv;
        float sv, cv;
        sincosf(ang, &sv, &cv);
        cs_tab[r][j] = cv;
        sn_tab[r][j] = sv;
    }

    // ---- load x tile (32 rows x 512, coalesced float4) ----
    {
        for (int i = tid; i < TT * (DMODEL / 4); i += 256) {
            int r  = i >> 7;             // /128
            int c4 = i & 127;
            const float4* src = reinterpret_cast<const float4*>(
                x + base + (long long)r * TSTRIDE);
            reinterpret_cast<float4*>(&x_tile[r][0])[c4] = src[c4];
        }
    }

    // per-thread output accumulators: cols {cb*64+c}, rows {r0..r0+7}
    float acc_o[8][8];
    #pragma unroll
    for (int a = 0; a < 8; ++a)
        #pragma unroll
        for (int bb = 0; bb < 8; ++bb) acc_o[a][bb] = 0.f;

    const int c  = tid & 63;
    const int r0 = (tid >> 6) * 8;

    __syncthreads();

    for (int h = 0; h < HEADS; ++h) {
        // ---------- qkv GEMM for head h:  [32x512] @ [512x64] x3 ----------
        #pragma unroll
        for (int m = 0; m < 3; ++m) {
            const float* wcol = w_qkv + (m * DMODEL + h * DHEAD + c);
            float acc[8];
            #pragma unroll
            for (int r = 0; r < 8; ++r) acc[r] = 0.f;
            for (int kk = 0; kk < DMODEL; kk += 4) {
                float w0 = wcol[(long long)(kk + 0) * (3 * DMODEL)];
                float w1 = wcol[(long long)(kk + 1) * (3 * DMODEL)];
                float w2 = wcol[(long long)(kk + 2) * (3 * DMODEL)];
                float w3 = wcol[(long long)(kk + 3) * (3 * DMODEL)];
                #pragma unroll
                for (int r = 0; r < 8; ++r) {
                    const float4 xv = *reinterpret_cast<const float4*>(&x_tile[r0 + r][kk]);
                    acc[r] += xv.x * w0 + xv.y * w1 + xv.z * w2 + xv.w * w3;
                }
            }
            float (*dst)[DHEAD + 1] = (m == 0) ? q_s : (m == 1) ? k_s : v_s;
            #pragma unroll
            for (int r = 0; r < 8; ++r) dst[r0 + r][c] = acc[r];
        }
        __syncthreads();

        // ---------- RoPE on q,k (first 32 dims, interleaved pairs) ----------
        for (int i = tid; i < TT * (ROT / 2) * 2; i += 256) {
            int mat = i >> 9;            // 0:q 1:k   (TT*16 = 512)
            int rem = i & 511;
            int r   = rem >> 4;
            int j   = rem & 15;
            float cv = cs_tab[r][j];
            float sv = sn_tab[r][j];
            float* p = mat ? &k_s[r][0] : &q_s[r][0];
            float x0 = p[2 * j], x1 = p[2 * j + 1];
            p[2 * j]     = x0 * cv - x1 * sv;
            p[2 * j + 1] = x1 * cv + x0 * sv;
        }
        __syncthreads();

        // ---------- scores = q k^T * scale, causal ----------
        for (int i = tid; i < TT * TT; i += 256) {
            int r  = i >> 5;
            int cc = i & 31;
            float acc = 0.f;
            if (cc <= r) {
                #pragma unroll 16
                for (int d = 0; d < DHEAD; ++d) acc += q_s[r][d] * k_s[cc][d];
                acc *= 0.125f;           // 1/sqrt(64)
            }
            s_s[r][cc] = acc;
        }
        __syncthreads();

        // ---------- row softmax (causal) ----------
        if (tid < TT) {
            int r = tid;
            float mx = -1e30f;
            for (int cc = 0; cc <= r; ++cc) mx = fmaxf(mx, s_s[r][cc]);
            float sum = 0.f;
            for (int cc = 0; cc <= r; ++cc) {
                float e = __expf(s_s[r][cc] - mx);
                s_s[r][cc] = e;
                sum += e;
            }
            float rs = 1.f / sum;
            for (int cc = 0; cc <= r; ++cc) s_s[r][cc] *= rs;
            for (int cc = r + 1; cc < TT; ++cc) s_s[r][cc] = 0.f;
        }
        __syncthreads();

        // ---------- PV: [32x32] @ [32x64] ----------
        {
            float acc[8];
            #pragma unroll
            for (int r = 0; r < 8; ++r) acc[r] = 0.f;
            for (int kk = 0; kk < TT; ++kk) {
                float vv = v_s[kk][c];
                #pragma unroll
                for (int r = 0; r < 8; ++r) acc[r] += s_s[r0 + r][kk] * vv;
            }
            #pragma unroll
            for (int r = 0; r < 8; ++r) pv_s[r0 + r][c] = acc[r];
        }
        __syncthreads();

        // ---------- partial out-projection: acc_o += pv_h @ w_out[h*64: , :] ----------
        {
            const float* wrow = w_out + (long long)(h * DHEAD) * DMODEL + c;
            for (int d = 0; d < DHEAD; ++d) {
                float wv[8];
                #pragma unroll
                for (int cb = 0; cb < 8; ++cb) wv[cb] = wrow[(long long)d * DMODEL + cb * 64];
                #pragma unroll
                for (int r = 0; r < 8; ++r) {
                    float a = pv_s[r0 + r][d];
                    #pragma unroll
                    for (int cb = 0; cb < 8; ++cb) acc_o[cb][r] += a * wv[cb];
                }
            }
        }
        __syncthreads();   // before next head overwrites q/k/v/s/pv
    }

    // ---------- write output (+bias), coalesced ----------
    #pragma unroll
    for (int cb = 0; cb < 8; ++cb) {
        int col = cb * 64 + c;
        float bias = b_out[col];
        #pragma unroll
        for (int r = 0; r < 8; ++r) {
            int t = r0 + r;
            long long off = ((long long)(b * TT + t) * HWSZ + hw) * DMODEL + col;
            out[off] = acc_o[cb][r] + bias;
        }
    }
}

extern "C" void kernel_launch(void* const* d_in, const int* in_sizes, int n_in,
                              void* d_out, int out_size, void* d_ws, size_t ws_size,
                              hipStream_t stream) {
    const float* x     = (const float*)d_in[0];
    const float* w_qkv = (const float*)d_in[1];
    const float* w_out = (const float*)d_in[2];
    const float* b_out = (const float*)d_in[3];
    float* out = (float*)d_out;
    (void)in_sizes; (void)n_in; (void)out_size; (void)d_ws; (void)ws_size;

    dim3 grid(2 * HWSZ);   // B * H * W = 2048 blocks
    dim3 block(256);
    taa_fused_kernel<<<grid, block, 0, stream>>>(x, w_qkv, w_out, b_out, out);
}

// Round 3
// 513.619 us; speedup vs baseline: 14.2388x; 14.2388x over previous
//
#include <hip/hip_runtime.h>
#include <hip/hip_bf16.h>
#include <math.h>

#define HEADS  8
#define DHEAD  64
#define TT     32
#define DMODEL 512
#define HWSZ   1024
#define TSTRIDE (HWSZ*DMODEL)

#define NQKV (3*DMODEL*DMODEL)   // 786432  w_qkv elements
#define NOUT (DMODEL*DMODEL)     // 262144  w_out elements
#define NTAB 512                 // 32 t x 16 freq rope entries

typedef __attribute__((ext_vector_type(8))) short bf16x8;   // 8 bf16 = 4 VGPR (MFMA A/B frag)
typedef __attribute__((ext_vector_type(4))) float f32x4;    // MFMA C/D frag
typedef __attribute__((ext_vector_type(4))) short s16x4;

__device__ __forceinline__ unsigned short f2bf(float f) {   // RNE f32->bf16
    unsigned int u = __builtin_bit_cast(unsigned int, f);
    u += 0x7FFFu + ((u >> 16) & 1u);
    return (unsigned short)(u >> 16);
}

// ---------------- prep: weights -> bf16 in MFMA-fragment order, rope tables ----
// fragment order: block (T,k05) of 1KB: element ((T*16+k05)*64 + lane)*8 + i
//   holds W_t[col = T*16 + lane%16][k = k05*32 + (lane/16)*8 + i]
__global__ __launch_bounds__(256)
void taa_prep(const float* __restrict__ wqkv, const float* __restrict__ wout,
              unsigned short* __restrict__ ws) {
    long i = (long)blockIdx.x * 256 + threadIdx.x;
    unsigned short* wqf = ws;
    unsigned short* wof = ws + NQKV;
    float* cs = (float*)(wof + NOUT);
    float* sn = cs + NTAB;
    if (i < NQKV) {
        int i8 = (int)(i & 7), lane = (int)((i >> 3) & 63), blk = (int)(i >> 9);
        int k05 = blk & 15, t = blk >> 4;                 // t < 96
        int n = t * 16 + (lane & 15);                     // col in w_qkv
        int k = k05 * 32 + (lane >> 4) * 8 + i8;          // row in w_qkv
        wqf[i] = f2bf(wqkv[(long)k * 1536 + n]);
    } else if (i < NQKV + NOUT) {
        long j = i - NQKV;
        int i8 = (int)(j & 7), lane = (int)((j >> 3) & 63), blk = (int)(j >> 9);
        int k05 = blk & 15, t = blk >> 4;                 // t < 32
        int col = t * 16 + (lane & 15);
        int k = k05 * 32 + (lane >> 4) * 8 + i8;
        wof[j] = f2bf(wout[(long)k * 512 + col]);
    } else if (i < NQKV + NOUT + NTAB) {
        int j = (int)(i - NQKV - NOUT);
        int t = j >> 4, f = j & 15;
        float inv = powf(10000.f, -(float)(2 * f) / 32.f);
        float sv, cv;
        sincosf((float)t * inv, &sv, &cv);
        cs[j] = cv; sn[j] = sv;
    }
}

// ---------------- LDS layout (byte offsets), XOR-swizzled rows -----------------
#define X_OFF  0            // x bf16 [32][512]  stride 1024B, 32768B
#define Q_OFF  32768        // q bf16 [32][64]   stride 128B,  4096B
#define K_OFF  36864        // k bf16 [32][64]
#define V_OFF  40960        // v^T bf16 [64 d][64(32 used) t] stride 128B, 8192B
#define P_OFF  49152        // probs bf16 [32][64(32 used)]
#define PV_OFF 53248        // attn out bf16 [32][64]
#define S_OFF  57344        // scores f32 [32][33] 4224B
#define CS_OFF 61568        // cos f32 [32][16]
#define SN_OFF 63616        // sin f32 [32][16]
#define LDS_SZ 65664

#define XS(r, cB) (X_OFF + ((((r) << 10) + (cB)) ^ (((r) & 7) << 4)))
#define RS(base, r, cB) ((base) + ((((r) << 7) + (cB)) ^ (((r) & 7) << 4)))

#define MFMA(a, b, c) __builtin_amdgcn_mfma_f32_16x16x32_bf16((a), (b), (c), 0, 0, 0)

__global__ __launch_bounds__(256, 2)
void taa_main(const float* __restrict__ x,
              const unsigned short* __restrict__ ws,
              const float* __restrict__ b_out,
              float* __restrict__ out) {
    __shared__ __align__(16) unsigned char smem[LDS_SZ];

    const unsigned short* wqf = ws;            // qkv weights, frag order
    const unsigned short* wof = ws + NQKV;     // out  weights, frag order
    const float* cs_g = (const float*)(wof + NOUT);
    const float* sn_g = cs_g + NTAB;

    const int tid  = threadIdx.x;
    const int lane = tid & 63;
    const int wv   = tid >> 6;                 // wave 0..3
    const int quad = lane >> 4;
    const int lid  = lane & 15;

    const int n  = blockIdx.x;
    const int b  = n >> 10;
    const int hw = n & 1023;
    const long long base = ((long long)b * TT * HWSZ + hw) * DMODEL;

    float* s_sc = (float*)(smem + S_OFF);
    float* cs_l = (float*)(smem + CS_OFF);
    float* sn_l = (float*)(smem + SN_OFF);

    // ---- rope tables global -> LDS ----
    for (int i = tid; i < NTAB; i += 256) { cs_l[i] = cs_g[i]; sn_l[i] = sn_g[i]; }

    // ---- stage x: fp32 global -> bf16 swizzled LDS (32x512) ----
    for (int idx = tid; idx < 2048; idx += 256) {        // 16B chunks
        int r  = idx >> 6;                               // row 0..31
        int c8 = idx & 63;                               // 8-elem group
        const float4* src = (const float4*)(x + base + (long long)r * TSTRIDE + c8 * 8);
        float4 f0 = src[0], f1 = src[1];
        s16x4 lo, hi;
        lo[0] = f2bf(f0.x); lo[1] = f2bf(f0.y); lo[2] = f2bf(f0.z); lo[3] = f2bf(f0.w);
        hi[0] = f2bf(f1.x); hi[1] = f2bf(f1.y); hi[2] = f2bf(f1.z); hi[3] = f2bf(f1.w);
        int a = XS(r, c8 * 16);
        *(s16x4*)(smem + a)     = lo;
        *(s16x4*)(smem + a + 8) = hi;
    }

    f32x4 oacc[16];
    #pragma unroll
    for (int i = 0; i < 16; ++i) oacc[i] = (f32x4){0.f, 0.f, 0.f, 0.f};

    __syncthreads();

    for (int h = 0; h < HEADS; ++h) {
        // ================= qkv GEMM (24 tiles of 16x16, K=512) =================
        for (int jt = 0; jt < 6; ++jt) {
            int tile = wv + jt * 4;            // 0..23
            int mt = tile / 12;                // row tile
            int j  = tile % 12;
            int m  = j >> 2;                   // 0=q 1=k 2=v
            int t16 = j & 3;                   // 16-col tile within head
            int T = m * 32 + h * 4 + t16;      // global col tile in w_qkv
            int arow = lid + 16 * mt;
            f32x4 acc = {0.f, 0.f, 0.f, 0.f};
            #pragma unroll 4
            for (int k05 = 0; k05 < 16; ++k05) {
                bf16x8 a = *(const bf16x8*)(smem + XS(arow, (k05 * 32 + 8 * quad) * 2));
                bf16x8 bw = *(const bf16x8*)(wqf + (((long)(T * 16 + k05)) * 512 + lane * 8));
                acc = MFMA(a, bw, acc);
            }
            if (m < 2) {
                int dst = (m == 0) ? Q_OFF : K_OFF;
                if (t16 < 2) {                 // rotary half (cols 0..31)
                    #pragma unroll
                    for (int r = 0; r < 4; ++r) {
                        float v = acc[r];
                        float p = __shfl_xor(v, 1, 64);
                        int trow = mt * 16 + quad * 4 + r;
                        int colh = t16 * 16 + lid;
                        int jj = colh >> 1;
                        float cv = cs_l[trow * 16 + jj];
                        float sv = sn_l[trow * 16 + jj];
                        float res = (colh & 1) ? (v * cv + p * sv) : (v * cv - p * sv);
                        *(unsigned short*)(smem + RS(dst, trow, colh * 2)) = f2bf(res);
                    }
                } else {
                    #pragma unroll
                    for (int r = 0; r < 4; ++r) {
                        int trow = mt * 16 + quad * 4 + r;
                        *(unsigned short*)(smem + RS(dst, trow, (t16 * 16 + lid) * 2)) = f2bf(acc[r]);
                    }
                }
            } else {                           // v: store transposed [d][t], packed 4x bf16
                int d  = t16 * 16 + lid;
                int t0 = mt * 16 + quad * 4;
                s16x4 pk;
                pk[0] = f2bf(acc[0]); pk[1] = f2bf(acc[1]);
                pk[2] = f2bf(acc[2]); pk[3] = f2bf(acc[3]);
                *(s16x4*)(smem + RS(V_OFF, d, t0 * 2)) = pk;
            }
        }
        __syncthreads();

        // ================= QK^T (4 tiles, one per wave) =================
        {
            int mt = wv >> 1, nt = wv & 1;
            f32x4 acc = {0.f, 0.f, 0.f, 0.f};
            #pragma unroll
            for (int d05 = 0; d05 < 2; ++d05) {
                bf16x8 a = *(const bf16x8*)(smem + RS(Q_OFF, lid + 16 * mt, (d05 * 32 + 8 * quad) * 2));
                bf16x8 bk = *(const bf16x8*)(smem + RS(K_OFF, lid + 16 * nt, (d05 * 32 + 8 * quad) * 2));
                acc = MFMA(a, bk, acc);
            }
            #pragma unroll
            for (int r = 0; r < 4; ++r) {
                int tq = mt * 16 + quad * 4 + r;
                int tk = nt * 16 + lid;
                s_sc[tq * 33 + tk] = acc[r] * 0.125f;
            }
        }
        __syncthreads();

        // ================= causal softmax (rows in parallel) =================
        if (tid < TT) {
            int r = tid;
            float mx = -1e30f;
            for (int cc = 0; cc <= r; ++cc) mx = fmaxf(mx, s_sc[r * 33 + cc]);
            float sum = 0.f;
            for (int cc = 0; cc <= r; ++cc) {
                float e = __expf(s_sc[r * 33 + cc] - mx);
                s_sc[r * 33 + cc] = e;
                sum += e;
            }
            float rs = 1.f / sum;
            for (int cc = 0; cc < TT; ++cc) {
                float pv = (cc <= r) ? s_sc[r * 33 + cc] * rs : 0.f;
                *(unsigned short*)(smem + RS(P_OFF, r, cc * 2)) = f2bf(pv);
            }
        }
        __syncthreads();

        // ================= PV (8 tiles: 2 per wave) =================
        {
            bf16x8 bv = *(const bf16x8*)(smem + RS(V_OFF, wv * 16 + lid, (8 * quad) * 2));
            #pragma unroll
            for (int mt = 0; mt < 2; ++mt) {
                bf16x8 a = *(const bf16x8*)(smem + RS(P_OFF, lid + 16 * mt, (8 * quad) * 2));
                f32x4 acc = {0.f, 0.f, 0.f, 0.f};
                acc = MFMA(a, bv, acc);
                #pragma unroll
                for (int r = 0; r < 4; ++r) {
                    int t = mt * 16 + quad * 4 + r;
                    int d = wv * 16 + lid;
                    *(unsigned short*)(smem + RS(PV_OFF, t, d * 2)) = f2bf(acc[r]);
                }
            }
        }
        __syncthreads();

        // ================= out-projection accumulate (persistent frags) ========
        {
            int mt = wv >> 1, half = wv & 1;
            #pragma unroll
            for (int nt = 0; nt < 16; ++nt) {
                int T = half * 16 + nt;
                #pragma unroll
                for (int k05 = 0; k05 < 2; ++k05) {
                    bf16x8 a = *(const bf16x8*)(smem + RS(PV_OFF, lid + 16 * mt, (k05 * 32 + 8 * quad) * 2));
                    bf16x8 bw = *(const bf16x8*)(wof + (((long)(T * 16 + h * 2 + k05)) * 512 + lane * 8));
                    oacc[nt] = MFMA(a, bw, oacc[nt]);
                }
            }
        }
        __syncthreads();   // before next head overwrites q/k/v/p/pv
    }

    // ================= write out (+bias) =================
    {
        int mt = wv >> 1, half = wv & 1;
        #pragma unroll
        for (int nt = 0; nt < 16; ++nt) {
            int col = (half * 16 + nt) * 16 + lid;
            float bias = b_out[col];
            #pragma unroll
            for (int r = 0; r < 4; ++r) {
                int t = mt * 16 + quad * 4 + r;
                out[base + (long long)t * TSTRIDE + col] = oacc[nt][r] + bias;
            }
        }
    }
}

extern "C" void kernel_launch(void* const* d_in, const int* in_sizes, int n_in,
                              void* d_out, int out_size, void* d_ws, size_t ws_size,
                              hipStream_t stream) {
    const float* x     = (const float*)d_in[0];
    const float* w_qkv = (const float*)d_in[1];
    const float* w_out = (const float*)d_in[2];
    const float* b_out = (const float*)d_in[3];
    float* out = (float*)d_out;
    (void)in_sizes; (void)n_in; (void)out_size; (void)ws_size;

    unsigned short* ws = (unsigned short*)d_ws;   // needs ~2.1 MB

    // prep: 786432 + 262144 + 512 = 1049088 items / 256 = 4098 blocks
    taa_prep<<<dim3(4098), dim3(256), 0, stream>>>(w_qkv, w_out, ws);
    taa_main<<<dim3(2048), dim3(256), 0, stream>>>(x, ws, b_out, out);
}

// Round 4
// 272.812 us; speedup vs baseline: 26.8071x; 1.8827x over previous
//
#include <hip/hip_runtime.h>
#include <hip/hip_bf16.h>
#include <math.h>

#define HEADS  8
#define TT     32
#define DMODEL 512
#define HWSZ   1024
#define TSTRIDE (HWSZ*DMODEL)

#define NQKV (3*DMODEL*DMODEL)   // 786432
#define NOUT (DMODEL*DMODEL)     // 262144
#define NTAB 512

typedef __attribute__((ext_vector_type(8))) short bf16x8;
typedef __attribute__((ext_vector_type(4))) float f32x4;
typedef __attribute__((ext_vector_type(4))) short s16x4;

__device__ __forceinline__ unsigned short f2bf(float f) {   // RNE f32->bf16
    unsigned int u = __builtin_bit_cast(unsigned int, f);
    u += 0x7FFFu + ((u >> 16) & 1u);
    return (unsigned short)(u >> 16);
}

// ---------------- prep: weights -> bf16 MFMA-fragment order + rope tables -----
// (unchanged from r3 — verified correct)
__global__ __launch_bounds__(256)
void taa_prep(const float* __restrict__ wqkv, const float* __restrict__ wout,
              unsigned short* __restrict__ ws) {
    long i = (long)blockIdx.x * 256 + threadIdx.x;
    unsigned short* wqf = ws;
    unsigned short* wof = ws + NQKV;
    float* cs = (float*)(wof + NOUT);
    float* sn = cs + NTAB;
    if (i < NQKV) {
        int i8 = (int)(i & 7), lane = (int)((i >> 3) & 63), blk = (int)(i >> 9);
        int k05 = blk & 15, t = blk >> 4;
        int n = t * 16 + (lane & 15);
        int k = k05 * 32 + (lane >> 4) * 8 + i8;
        wqf[i] = f2bf(wqkv[(long)k * 1536 + n]);
    } else if (i < NQKV + NOUT) {
        long j = i - NQKV;
        int i8 = (int)(j & 7), lane = (int)((j >> 3) & 63), blk = (int)(j >> 9);
        int k05 = blk & 15, t = blk >> 4;
        int col = t * 16 + (lane & 15);
        int k = k05 * 32 + (lane >> 4) * 8 + i8;
        wof[j] = f2bf(wout[(long)k * 512 + col]);
    } else if (i < NQKV + NOUT + NTAB) {
        int j = (int)(i - NQKV - NOUT);
        int t = j >> 4, f = j & 15;
        float inv = powf(10000.f, -(float)(2 * f) / 32.f);
        float sv, cv;
        sincosf((float)t * inv, &sv, &cv);
        cs[j] = cv; sn[j] = sv;
    }
}

// ---------------- LDS layout (bytes), XOR-swizzled 128B/1024B-stride rows -----
#define X_OFF  0            // x bf16 [2][32][512]  row stride 1024B   65536
#define Q_OFF  65536        // q bf16 [2][32][64]   row stride 128B     8192
#define K_OFF  73728        // k bf16 [2][32][64]                       8192
#define V_OFF  81920        // v^T bf16 [2][64 d][64 t]                16384
#define P_OFF  98304        // probs bf16 [2][32][64]                   8192
#define PV_OFF 106496       // attn out bf16 [2][32][64]                8192
#define S_OFF  114688       // scores f32 [2][32][33]                   8448
#define CS_OFF 123136       // cos f32 [512]                            2048
#define SN_OFF 125184       // sin f32 [512]                            2048
#define LDS_SZ 127232

#define XS(g, r, cB) (X_OFF + ((g) << 15) + ((r) << 10) + ((cB) ^ (((r) & 7) << 4)))
#define RS(base, r, cB) ((base) + ((r) << 7) + ((cB) ^ (((r) & 7) << 4)))

#define MFMA(a, b, c) __builtin_amdgcn_mfma_f32_16x16x32_bf16((a), (b), (c), 0, 0, 0)

__global__ __launch_bounds__(512, 2)
void taa_main(const float* __restrict__ x,
              const unsigned short* __restrict__ ws,
              const float* __restrict__ b_out,
              float* __restrict__ out) {
    extern __shared__ __align__(16) unsigned char smem[];

    const unsigned short* wqf = ws;
    const unsigned short* wof = ws + NQKV;
    const float* cs_gl = (const float*)(wof + NOUT);
    const float* sn_gl = cs_gl + NTAB;

    const int tid  = threadIdx.x;
    const int lane = tid & 63;
    const int wv   = tid >> 6;                 // wave 0..7
    const int quad = lane >> 4;
    const int lid  = lane & 15;

    const int n0 = blockIdx.x * 2;
    const long long base0 = ((long long)(n0 >> 10) * (TT * HWSZ) + (n0 & 1023)) * DMODEL;
    const int n1 = n0 + 1;
    const long long base1 = ((long long)(n1 >> 10) * (TT * HWSZ) + (n1 & 1023)) * DMODEL;

    float* cs_l = (float*)(smem + CS_OFF);
    float* sn_l = (float*)(smem + SN_OFF);
    for (int i = tid; i < NTAB; i += 512) { cs_l[i] = cs_gl[i]; sn_l[i] = sn_gl[i]; }

    // ---- stage x (both groups): fp32 global -> bf16 swizzled LDS ----
    for (int idx = tid; idx < 4096; idx += 512) {       // 16B bf16 chunks
        int g  = idx >> 11;
        int r  = (idx >> 6) & 31;
        int c8 = idx & 63;
        long long bg = g ? base1 : base0;
        const float4* src = (const float4*)(x + bg + (long long)r * TSTRIDE + c8 * 8);
        float4 f0 = src[0], f1 = src[1];
        s16x4 lo, hi;
        lo[0] = (short)f2bf(f0.x); lo[1] = (short)f2bf(f0.y);
        lo[2] = (short)f2bf(f0.z); lo[3] = (short)f2bf(f0.w);
        hi[0] = (short)f2bf(f1.x); hi[1] = (short)f2bf(f1.y);
        hi[2] = (short)f2bf(f1.z); hi[3] = (short)f2bf(f1.w);
        int a = XS(g, r, c8 * 16);
        *(s16x4*)(smem + a)     = lo;
        *(s16x4*)(smem + a + 8) = hi;
    }

    f32x4 oacc[4][2][2];                       // [col-tile j][group][row-tile]
    #pragma unroll
    for (int j = 0; j < 4; ++j)
        #pragma unroll
        for (int g = 0; g < 2; ++g)
            #pragma unroll
            for (int mt = 0; mt < 2; ++mt) oacc[j][g][mt] = (f32x4){0.f, 0.f, 0.f, 0.f};

    __syncthreads();

    for (int h = 0; h < HEADS; ++h) {
        // ===== qkv GEMM: 12 col-tiles, each B-frag feeds 4 A-tiles (2g x 2mt) =====
        for (int rnd = 0; rnd < 2; ++rnd) {
            if (rnd == 1 && wv >= 4) break;            // wave-uniform
            int ct  = (rnd == 0) ? wv : 8 + wv;        // 0..11
            int m   = ct >> 2;                         // 0=q 1=k 2=v
            int t16 = ct & 3;
            int T   = m * 32 + h * 4 + t16;
            const unsigned short* wp = wqf + ((long)T * 16) * 512 + lane * 8;
            f32x4 acc[2][2];
            #pragma unroll
            for (int g = 0; g < 2; ++g)
                #pragma unroll
                for (int mt = 0; mt < 2; ++mt) acc[g][mt] = (f32x4){0.f, 0.f, 0.f, 0.f};
            #pragma unroll 4
            for (int k05 = 0; k05 < 16; ++k05) {
                bf16x8 bw = *(const bf16x8*)(wp + (long)k05 * 512);
                #pragma unroll
                for (int g = 0; g < 2; ++g)
                    #pragma unroll
                    for (int mt = 0; mt < 2; ++mt) {
                        bf16x8 a = *(const bf16x8*)(smem + XS(g, lid + 16 * mt, k05 * 64 + quad * 16));
                        acc[g][mt] = MFMA(a, bw, acc[g][mt]);
                    }
            }
            if (m < 2) {
                int dstb = (m == 0) ? Q_OFF : K_OFF;
                if (t16 < 2) {                         // rotary cols 0..31
                    #pragma unroll
                    for (int g = 0; g < 2; ++g)
                        #pragma unroll
                        for (int mt = 0; mt < 2; ++mt)
                            #pragma unroll
                            for (int r = 0; r < 4; ++r) {
                                float v = acc[g][mt][r];
                                float p = __shfl_xor(v, 1, 64);
                                int trow = mt * 16 + quad * 4 + r;
                                int colh = t16 * 16 + lid;
                                int jj = colh >> 1;
                                float cv = cs_l[trow * 16 + jj];
                                float sv = sn_l[trow * 16 + jj];
                                float res = (colh & 1) ? (v * cv + p * sv) : (v * cv - p * sv);
                                *(unsigned short*)(smem + RS(dstb + g * 4096, trow, colh * 2)) = f2bf(res);
                            }
                } else {
                    #pragma unroll
                    for (int g = 0; g < 2; ++g)
                        #pragma unroll
                        for (int mt = 0; mt < 2; ++mt)
                            #pragma unroll
                            for (int r = 0; r < 4; ++r) {
                                int trow = mt * 16 + quad * 4 + r;
                                *(unsigned short*)(smem + RS(dstb + g * 4096, trow, (t16 * 16 + lid) * 2)) = f2bf(acc[g][mt][r]);
                            }
                }
            } else {                                   // v -> transposed [d][t]
                #pragma unroll
                for (int g = 0; g < 2; ++g)
                    #pragma unroll
                    for (int mt = 0; mt < 2; ++mt) {
                        int d  = t16 * 16 + lid;
                        int t0 = mt * 16 + quad * 4;
                        s16x4 pk;
                        pk[0] = (short)f2bf(acc[g][mt][0]); pk[1] = (short)f2bf(acc[g][mt][1]);
                        pk[2] = (short)f2bf(acc[g][mt][2]); pk[3] = (short)f2bf(acc[g][mt][3]);
                        *(s16x4*)(smem + RS(V_OFF + g * 8192, d, t0 * 2)) = pk;
                    }
            }
        }
        __syncthreads();

        // ===== QK^T: 8 tiles, one per wave =====
        {
            int g = wv >> 2, mt = (wv >> 1) & 1, nt = wv & 1;
            f32x4 acc = {0.f, 0.f, 0.f, 0.f};
            #pragma unroll
            for (int d05 = 0; d05 < 2; ++d05) {
                bf16x8 a  = *(const bf16x8*)(smem + RS(Q_OFF + g * 4096, lid + 16 * mt, d05 * 64 + quad * 16));
                bf16x8 bk = *(const bf16x8*)(smem + RS(K_OFF + g * 4096, lid + 16 * nt, d05 * 64 + quad * 16));
                acc = MFMA(a, bk, acc);
            }
            float* sg = (float*)(smem + S_OFF + g * 4224);
            #pragma unroll
            for (int r = 0; r < 4; ++r)
                sg[(mt * 16 + quad * 4 + r) * 33 + nt * 16 + lid] = acc[r] * 0.125f;
        }
        __syncthreads();

        // ===== causal softmax: 64 rows x 8 lanes, all 512 threads =====
        {
            int row = tid >> 3;
            int g = row >> 5, r = row & 31;
            int sub = tid & 7;
            const float* sg = (const float*)(smem + S_OFF + g * 4224);
            float vals[4];
            float mx = -1e30f;
            #pragma unroll
            for (int jj = 0; jj < 4; ++jj) {
                int cc = sub * 4 + jj;
                float v = (cc <= r) ? sg[r * 33 + cc] : -1e30f;
                vals[jj] = v;
                mx = fmaxf(mx, v);
            }
            mx = fmaxf(mx, __shfl_xor(mx, 1, 64));
            mx = fmaxf(mx, __shfl_xor(mx, 2, 64));
            mx = fmaxf(mx, __shfl_xor(mx, 4, 64));
            float sum = 0.f;
            #pragma unroll
            for (int jj = 0; jj < 4; ++jj) {
                int cc = sub * 4 + jj;
                float e = (cc <= r) ? __expf(vals[jj] - mx) : 0.f;
                vals[jj] = e;
                sum += e;
            }
            sum += __shfl_xor(sum, 1, 64);
            sum += __shfl_xor(sum, 2, 64);
            sum += __shfl_xor(sum, 4, 64);
            float rs = 1.f / sum;
            s16x4 pk;
            #pragma unroll
            for (int jj = 0; jj < 4; ++jj) pk[jj] = (short)f2bf(vals[jj] * rs);
            *(s16x4*)(smem + RS(P_OFF + g * 4096, r, sub * 8)) = pk;
        }
        __syncthreads();

        // ===== PV: 16 tiles, 2 per wave =====
        {
            int g = wv >> 2, mt = (wv >> 1) & 1, ntp = (wv & 1) * 2;
            bf16x8 a = *(const bf16x8*)(smem + RS(P_OFF + g * 4096, lid + 16 * mt, quad * 16));
            #pragma unroll
            for (int j = 0; j < 2; ++j) {
                int nt = ntp + j;
                bf16x8 bv = *(const bf16x8*)(smem + RS(V_OFF + g * 8192, nt * 16 + lid, quad * 16));
                f32x4 acc = MFMA(a, bv, ((f32x4){0.f, 0.f, 0.f, 0.f}));
                #pragma unroll
                for (int r = 0; r < 4; ++r) {
                    int t = mt * 16 + quad * 4 + r;
                    int d = nt * 16 + lid;
                    *(unsigned short*)(smem + RS(PV_OFF + g * 4096, t, d * 2)) = f2bf(acc[r]);
                }
            }
        }
        __syncthreads();

        // ===== out-projection accumulate: B loaded once/block, 4 MFMA per load =====
        {
            #pragma unroll
            for (int k05h = 0; k05h < 2; ++k05h) {
                int kb = h * 2 + k05h;
                bf16x8 a[2][2];
                #pragma unroll
                for (int g = 0; g < 2; ++g)
                    #pragma unroll
                    for (int mt = 0; mt < 2; ++mt)
                        a[g][mt] = *(const bf16x8*)(smem + RS(PV_OFF + g * 4096, lid + 16 * mt, k05h * 64 + quad * 16));
                #pragma unroll
                for (int j = 0; j < 4; ++j) {
                    int ct = wv + 8 * j;
                    bf16x8 bw = *(const bf16x8*)(wof + ((long)(ct * 16 + kb)) * 512 + lane * 8);
                    #pragma unroll
                    for (int g = 0; g < 2; ++g)
                        #pragma unroll
                        for (int mt = 0; mt < 2; ++mt)
                            oacc[j][g][mt] = MFMA(a[g][mt], bw, oacc[j][g][mt]);
                }
            }
        }
        __syncthreads();   // before next head overwrites q/k/v/p/pv
    }

    // ===== write out (+bias) =====
    #pragma unroll
    for (int j = 0; j < 4; ++j) {
        int col = (wv + 8 * j) * 16 + lid;
        float bias = b_out[col];
        #pragma unroll
        for (int g = 0; g < 2; ++g) {
            long long bg = g ? base1 : base0;
            #pragma unroll
            for (int mt = 0; mt < 2; ++mt)
                #pragma unroll
                for (int r = 0; r < 4; ++r) {
                    int t = mt * 16 + quad * 4 + r;
                    out[bg + (long long)t * TSTRIDE + col] = oacc[j][g][mt][r] + bias;
                }
        }
    }
}

extern "C" void kernel_launch(void* const* d_in, const int* in_sizes, int n_in,
                              void* d_out, int out_size, void* d_ws, size_t ws_size,
                              hipStream_t stream) {
    const float* x     = (const float*)d_in[0];
    const float* w_qkv = (const float*)d_in[1];
    const float* w_out = (const float*)d_in[2];
    const float* b_out = (const float*)d_in[3];
    float* out = (float*)d_out;
    (void)in_sizes; (void)n_in; (void)out_size; (void)ws_size;

    unsigned short* ws = (unsigned short*)d_ws;   // ~2.1 MB

    taa_prep<<<dim3(4098), dim3(256), 0, stream>>>(w_qkv, w_out, ws);
    taa_main<<<dim3(1024), dim3(512), LDS_SZ, stream>>>(x, ws, b_out, out);
}

// Round 5
// 239.436 us; speedup vs baseline: 30.5439x; 1.1394x over previous
//
#include <hip/hip_runtime.h>
#include <hip/hip_bf16.h>
#include <math.h>

#define HEADS  8
#define TT     32
#define DMODEL 512
#define HWSZ   1024
#define TSTRIDE (HWSZ*DMODEL)

#define NQKV (3*DMODEL*DMODEL)   // 786432
#define NOUT (DMODEL*DMODEL)     // 262144
#define NTAB 512

typedef __attribute__((ext_vector_type(8)))  short bf16x8;
typedef __attribute__((ext_vector_type(4)))  float f32x4;
typedef __attribute__((ext_vector_type(16))) float f32x16;
typedef __attribute__((ext_vector_type(4)))  short s16x4;

__device__ __forceinline__ unsigned short f2bf(float f) {   // RNE f32->bf16
    unsigned int u = __builtin_bit_cast(unsigned int, f);
    u += 0x7FFFu + ((u >> 16) & 1u);
    return (unsigned short)(u >> 16);
}

// ---------------- prep: weights -> bf16 MFMA-fragment order + rope tables -----
__global__ __launch_bounds__(256)
void taa_prep(const float* __restrict__ wqkv, const float* __restrict__ wout,
              unsigned short* __restrict__ ws) {
    long i = (long)blockIdx.x * 256 + threadIdx.x;
    unsigned short* wqf = ws;
    unsigned short* wof = ws + NQKV;
    float* cs = (float*)(wof + NOUT);
    float* sn = cs + NTAB;
    if (i < NQKV) {
        int i8 = (int)(i & 7), lane = (int)((i >> 3) & 63), blk = (int)(i >> 9);
        int k05 = blk & 15, t = blk >> 4;
        int n = t * 16 + (lane & 15);
        int k = k05 * 32 + (lane >> 4) * 8 + i8;
        wqf[i] = f2bf(wqkv[(long)k * 1536 + n]);
    } else if (i < NQKV + NOUT) {
        long j = i - NQKV;
        int i8 = (int)(j & 7), lane = (int)((j >> 3) & 63), blk = (int)(j >> 9);
        int k05 = blk & 15, t = blk >> 4;
        int col = t * 16 + (lane & 15);
        int k = k05 * 32 + (lane >> 4) * 8 + i8;
        wof[j] = f2bf(wout[(long)k * 512 + col]);
    } else if (i < NQKV + NOUT + NTAB) {
        int j = (int)(i - NQKV - NOUT);
        int t = j >> 4, f = j & 15;
        float inv = powf(10000.f, -(float)(2 * f) / 32.f);
        float sv, cv;
        sincosf((float)t * inv, &sv, &cv);
        cs[j] = cv; sn[j] = sv;
    }
}

// ---------------- LDS layout (bytes) ------------------------------------------
// X  [2g][32][512]bf16 swizzled rows (1024B stride)           65536
// Q  [2g][2h][32][64]bf16 row-major, 128B stride, RS swizzle  16384
// K  same                                                     16384
// V^T[2g][2h][64][32]bf16, 64B stride, VS swizzle             16384
// PV [2g][2h][32][64]bf16, 128B stride, RS swizzle            16384
// cos/sin f32[512] each                                        4096
#define X_OFF  0
#define Q_OFF  65536
#define K_OFF  81920
#define V_OFF  98304
#define PV_OFF 114688
#define CS_OFF 131072
#define SN_OFF 133120
#define LDS_SZ 135168

#define XS(g, r, cB) (X_OFF + ((g) << 15) + ((r) << 10) + ((cB) ^ (((r) & 7) << 4)))
#define RS(base, r, cB) ((base) + ((r) << 7) + ((cB) ^ (((r) & 7) << 4)))
#define VS(base, d, cB) ((base) + ((d) << 6) + ((cB) ^ (((d) & 7) << 3)))

#define MFMA16(a, b, c) __builtin_amdgcn_mfma_f32_16x16x32_bf16((a), (b), (c), 0, 0, 0)
#define MFMA32(a, b, c) __builtin_amdgcn_mfma_f32_32x32x16_bf16((a), (b), (c), 0, 0, 0)

__global__ __launch_bounds__(512, 1)
void taa_main(const float* __restrict__ x,
              const unsigned short* __restrict__ ws,
              const float* __restrict__ b_out,
              float* __restrict__ out) {
    extern __shared__ __align__(16) unsigned char smem[];

    const unsigned short* wqf = ws;
    const unsigned short* wof = ws + NQKV;
    const float* cs_gl = (const float*)(wof + NOUT);
    const float* sn_gl = cs_gl + NTAB;

    const int tid  = threadIdx.x;
    const int lane = tid & 63;
    const int wv   = tid >> 6;                 // wave 0..7
    const int quad = lane >> 4;
    const int lid  = lane & 15;

    const int n0 = blockIdx.x * 2;
    const long long base0 = ((long long)(n0 >> 10) * (TT * HWSZ) + (n0 & 1023)) * DMODEL;
    const int n1 = n0 + 1;
    const long long base1 = ((long long)(n1 >> 10) * (TT * HWSZ) + (n1 & 1023)) * DMODEL;

    float* cs_l = (float*)(smem + CS_OFF);
    float* sn_l = (float*)(smem + SN_OFF);
    for (int i = tid; i < NTAB; i += 512) { cs_l[i] = cs_gl[i]; sn_l[i] = sn_gl[i]; }

    // ---- stage x (both groups): fp32 global -> bf16 swizzled LDS ----
    for (int idx = tid; idx < 4096; idx += 512) {
        int g  = idx >> 11;
        int r  = (idx >> 6) & 31;
        int c8 = idx & 63;
        long long bg = g ? base1 : base0;
        const float4* src = (const float4*)(x + bg + (long long)r * TSTRIDE + c8 * 8);
        float4 f0 = src[0], f1 = src[1];
        s16x4 lo, hi;
        lo[0] = (short)f2bf(f0.x); lo[1] = (short)f2bf(f0.y);
        lo[2] = (short)f2bf(f0.z); lo[3] = (short)f2bf(f0.w);
        hi[0] = (short)f2bf(f1.x); hi[1] = (short)f2bf(f1.y);
        hi[2] = (short)f2bf(f1.z); hi[3] = (short)f2bf(f1.w);
        int a = XS(g, r, c8 * 16);
        *(s16x4*)(smem + a)     = lo;
        *(s16x4*)(smem + a + 8) = hi;
    }

    f32x4 oacc[4][2][2];                       // [col-tile j][group][row-tile]
    #pragma unroll
    for (int j = 0; j < 4; ++j)
        #pragma unroll
        for (int g = 0; g < 2; ++g)
            #pragma unroll
            for (int mt = 0; mt < 2; ++mt) oacc[j][g][mt] = (f32x4){0.f, 0.f, 0.f, 0.f};

    __syncthreads();

    for (int it = 0; it < 4; ++it) {           // 2 heads per iteration
        const int hpair = it * 2;

        // ===== qkv GEMM: 24 col-tiles (2 heads), 3 balanced rounds of 8 waves ====
        for (int rnd = 0; rnd < 3; ++rnd) {
            int ct  = rnd * 8 + wv;            // 0..23
            int m   = ct >> 3;                 // 0=q 1=k 2=v
            int hh  = (ct >> 2) & 1;
            int t16 = ct & 3;
            int T   = m * 32 + (hpair + hh) * 4 + t16;
            const unsigned short* wp = wqf + ((long)T * 16) * 512 + lane * 8;
            f32x4 acc[2][2];
            #pragma unroll
            for (int g = 0; g < 2; ++g)
                #pragma unroll
                for (int mt = 0; mt < 2; ++mt) acc[g][mt] = (f32x4){0.f, 0.f, 0.f, 0.f};
            #pragma unroll 4
            for (int k05 = 0; k05 < 16; ++k05) {
                bf16x8 bw = *(const bf16x8*)(wp + (long)k05 * 512);
                #pragma unroll
                for (int g = 0; g < 2; ++g)
                    #pragma unroll
                    for (int mt = 0; mt < 2; ++mt) {
                        bf16x8 a = *(const bf16x8*)(smem + XS(g, lid + 16 * mt, k05 * 64 + quad * 16));
                        acc[g][mt] = MFMA16(a, bw, acc[g][mt]);
                    }
            }
            if (m < 2) {                       // q,k: row-major [t][64] with RoPE
                int dstb = ((m == 0) ? Q_OFF : K_OFF) + hh * 4096;
                if (t16 < 2) {                 // rotary cols 0..31
                    #pragma unroll
                    for (int g = 0; g < 2; ++g)
                        #pragma unroll
                        for (int mt = 0; mt < 2; ++mt)
                            #pragma unroll
                            for (int r = 0; r < 4; ++r) {
                                float v = acc[g][mt][r];
                                float p = __shfl_xor(v, 1, 64);
                                int trow = mt * 16 + quad * 4 + r;
                                int colh = t16 * 16 + lid;
                                int jj = colh >> 1;
                                float cv = cs_l[trow * 16 + jj];
                                float sv = sn_l[trow * 16 + jj];
                                float res = (colh & 1) ? (v * cv + p * sv) : (v * cv - p * sv);
                                *(unsigned short*)(smem + RS(dstb + g * 8192, trow, colh * 2)) = f2bf(res);
                            }
                } else {
                    #pragma unroll
                    for (int g = 0; g < 2; ++g)
                        #pragma unroll
                        for (int mt = 0; mt < 2; ++mt)
                            #pragma unroll
                            for (int r = 0; r < 4; ++r) {
                                int trow = mt * 16 + quad * 4 + r;
                                *(unsigned short*)(smem + RS(dstb + g * 8192, trow, (t16 * 16 + lid) * 2)) = f2bf(acc[g][mt][r]);
                            }
                }
            } else {                           // v -> V^T [64 d][32 t], 64B rows
                #pragma unroll
                for (int g = 0; g < 2; ++g)
                    #pragma unroll
                    for (int mt = 0; mt < 2; ++mt) {
                        int d  = t16 * 16 + lid;
                        int t0 = mt * 16 + quad * 4;
                        s16x4 pk;
                        pk[0] = (short)f2bf(acc[g][mt][0]); pk[1] = (short)f2bf(acc[g][mt][1]);
                        pk[2] = (short)f2bf(acc[g][mt][2]); pk[3] = (short)f2bf(acc[g][mt][3]);
                        *(s16x4*)(smem + VS(V_OFF + (g * 2 + hh) * 4096, d, t0 * 2)) = pk;
                    }
            }
        }
        __syncthreads();

        // ===== attention: one (g,head,d-half) problem per wave, register-only ====
        {
            int g  = wv >> 2;
            int hh = (wv >> 1) & 1;
            int dt = wv & 1;
            int qr  = Q_OFF  + (g * 2 + hh) * 4096;
            int kr  = K_OFF  + (g * 2 + hh) * 4096;
            int vr  = V_OFF  + (g * 2 + hh) * 4096;
            int pvr = PV_OFF + (g * 2 + hh) * 4096;
            int tq = lane & 31;
            int hf = lane >> 5;

            // S^T = K · Q^T : D[m=t_k][n=t_q]
            f32x16 sc = {0.f,0.f,0.f,0.f,0.f,0.f,0.f,0.f,0.f,0.f,0.f,0.f,0.f,0.f,0.f,0.f};
            #pragma unroll
            for (int j = 0; j < 4; ++j) {
                bf16x8 aK = *(const bf16x8*)(smem + RS(kr, tq, j * 32 + hf * 16));
                bf16x8 bQ = *(const bf16x8*)(smem + RS(qr, tq, j * 32 + hf * 16));
                sc = MFMA32(aK, bQ, sc);
            }
            // causal mask + softmax over t_k (16 regs + cross-half shfl)
            float pe[16];
            float mx = -1e30f;
            #pragma unroll
            for (int r = 0; r < 16; ++r) {
                int tk = (r & 3) + 8 * (r >> 2) + 4 * hf;
                float v = (tk <= tq) ? sc[r] * 0.125f : -1e30f;
                pe[r] = v;
                mx = fmaxf(mx, v);
            }
            mx = fmaxf(mx, __shfl_xor(mx, 32, 64));
            float sum = 0.f;
            #pragma unroll
            for (int r = 0; r < 16; ++r) {
                float e = __expf(pe[r] - mx);
                pe[r] = e;
                sum += e;
            }
            sum += __shfl_xor(sum, 32, 64);
            float inv = 1.f / sum;
            bf16x8 pa0, pa1;
            #pragma unroll
            for (int i = 0; i < 8; ++i) {
                pa0[i] = (short)f2bf(pe[i] * inv);
                pa1[i] = (short)f2bf(pe[8 + i] * inv);
            }
            // PV: O[t_q][d] — lane's own P regs pair with split V reads
            // (k-slot mapping applied identically on A and B sides)
            int d = dt * 32 + tq;
            f32x16 o = {0.f,0.f,0.f,0.f,0.f,0.f,0.f,0.f,0.f,0.f,0.f,0.f,0.f,0.f,0.f,0.f};
            {
                s16x4 lo = *(const s16x4*)(smem + VS(vr, d, 8 * hf));
                s16x4 hi = *(const s16x4*)(smem + VS(vr, d, 16 + 8 * hf));
                bf16x8 bv;
                bv[0] = lo[0]; bv[1] = lo[1]; bv[2] = lo[2]; bv[3] = lo[3];
                bv[4] = hi[0]; bv[5] = hi[1]; bv[6] = hi[2]; bv[7] = hi[3];
                o = MFMA32(pa0, bv, o);
            }
            {
                s16x4 lo = *(const s16x4*)(smem + VS(vr, d, 32 + 8 * hf));
                s16x4 hi = *(const s16x4*)(smem + VS(vr, d, 48 + 8 * hf));
                bf16x8 bv;
                bv[0] = lo[0]; bv[1] = lo[1]; bv[2] = lo[2]; bv[3] = lo[3];
                bv[4] = hi[0]; bv[5] = hi[1]; bv[6] = hi[2]; bv[7] = hi[3];
                o = MFMA32(pa1, bv, o);
            }
            // store PV row-major [t][64]
            #pragma unroll
            for (int r = 0; r < 16; ++r) {
                int t = (r & 3) + 8 * (r >> 2) + 4 * hf;
                *(unsigned short*)(smem + RS(pvr, t, 2 * d)) = f2bf(o[r]);
            }
        }
        __syncthreads();

        // ===== out-projection accumulate (K-slice = this head pair, 128 wide) ====
        {
            #pragma unroll
            for (int k05h = 0; k05h < 4; ++k05h) {
                int hh   = k05h >> 1;
                int dblk = k05h & 1;
                int kb   = (hpair + hh) * 2 + dblk;
                bf16x8 a[2][2];
                #pragma unroll
                for (int g = 0; g < 2; ++g)
                    #pragma unroll
                    for (int mt = 0; mt < 2; ++mt)
                        a[g][mt] = *(const bf16x8*)(smem + RS(PV_OFF + (g * 2 + hh) * 4096, lid + 16 * mt, dblk * 64 + quad * 16));
                #pragma unroll
                for (int j = 0; j < 4; ++j) {
                    int ct = wv + 8 * j;
                    bf16x8 bw = *(const bf16x8*)(wof + ((long)(ct * 16 + kb)) * 512 + lane * 8);
                    #pragma unroll
                    for (int g = 0; g < 2; ++g)
                        #pragma unroll
                        for (int mt = 0; mt < 2; ++mt)
                            oacc[j][g][mt] = MFMA16(a[g][mt], bw, oacc[j][g][mt]);
                }
            }
        }
        // no barrier: next-iter qkv writes Q/K/V (readers synced at attn barrier);
        // next-iter attn writes PV only after next qkv barrier.
    }

    // ===== write out (+bias) =====
    #pragma unroll
    for (int j = 0; j < 4; ++j) {
        int col = (wv + 8 * j) * 16 + lid;
        float bias = b_out[col];
        #pragma unroll
        for (int g = 0; g < 2; ++g) {
            long long bg = g ? base1 : base0;
            #pragma unroll
            for (int mt = 0; mt < 2; ++mt)
                #pragma unroll
                for (int r = 0; r < 4; ++r) {
                    int t = mt * 16 + quad * 4 + r;
                    out[bg + (long long)t * TSTRIDE + col] = oacc[j][g][mt][r] + bias;
                }
        }
    }
}

extern "C" void kernel_launch(void* const* d_in, const int* in_sizes, int n_in,
                              void* d_out, int out_size, void* d_ws, size_t ws_size,
                              hipStream_t stream) {
    const float* x     = (const float*)d_in[0];
    const float* w_qkv = (const float*)d_in[1];
    const float* w_out = (const float*)d_in[2];
    const float* b_out = (const float*)d_in[3];
    float* out = (float*)d_out;
    (void)in_sizes; (void)n_in; (void)out_size; (void)ws_size;

    unsigned short* ws = (unsigned short*)d_ws;   // ~2.1 MB

    taa_prep<<<dim3(4098), dim3(256), 0, stream>>>(w_qkv, w_out, ws);
    taa_main<<<dim3(1024), dim3(512), LDS_SZ, stream>>>(x, ws, b_out, out);
}